// Round 13
// baseline (2371.668 us; speedup 1.0000x reference)
//
#include <hip/hip_runtime.h>
#include <stdint.h>

#define SEQ    512
#define NBATCH 64
#define HID    1024
#define GDIM   4096

typedef __attribute__((ext_vector_type(4))) float          f32x4;
typedef __attribute__((ext_vector_type(8))) short          s16x8;
typedef __attribute__((ext_vector_type(4))) unsigned short u16x4;
typedef __attribute__((ext_vector_type(4))) unsigned int   u32x4;

#define MFMA_BF16(a,b,c) __builtin_amdgcn_mfma_f32_16x16x32_bf16((a),(b),(c),0,0,0)

__device__ __forceinline__ unsigned short f2bf(float f){
  union { float f; unsigned u; } v; v.f = f;
  unsigned r = v.u + 0x7fffu + ((v.u >> 16) & 1u);
  return (unsigned short)(r >> 16);
}

__device__ __forceinline__ void gload_lds16(const void* g, void* l){
  __builtin_amdgcn_global_load_lds((const __attribute__((address_space(1))) void*)g,
                                   (__attribute__((address_space(3))) void*)l,
                                   16, 0, 0);
}

// ---------------- fp32 -> bf16 bulk convert (n4 = elements/4) ----------------
__global__ __launch_bounds__(256) void cvt_bf16(const float* __restrict__ s,
                                                unsigned short* __restrict__ d, int n4){
  int i = blockIdx.x*256 + threadIdx.x;
  if (i >= n4) return;
  f32x4 v = *(const f32x4*)(s + (size_t)i*4);
  u16x4 o;
  o[0]=f2bf(v[0]); o[1]=f2bf(v[1]); o[2]=f2bf(v[2]); o[3]=f2bf(v[3]);
  *(u16x4*)(d + (size_t)i*4) = o;
}

// ---------------- init: h0 -> hring slot 0 (bf16, linear), c0 -> cstate ----
__global__ __launch_bounds__(256) void init_state(const float* __restrict__ h0,
                                                  const float* __restrict__ c0,
                                                  unsigned short* __restrict__ hring,
                                                  float* __restrict__ cstate){
  int i = blockIdx.x*256 + threadIdx.x;   // 65536 total
  hring[i]  = f2bf(h0[i]);
  cstate[i] = c0[i];
}

// ---------------- x_proj GEMM: C[M][4096] = A[M][1024] * Bw[4096][1024]^T + bias ----
__global__ __launch_bounds__(256,1) void gemm_xproj(
    const unsigned short* __restrict__ A,
    const unsigned short* __restrict__ Bw,
    const float* __restrict__ bih, const float* __restrict__ bhh,
    float* __restrict__ C, int M)
{
  __shared__ unsigned short Al[2][128*64];
  __shared__ unsigned short Bl[2][128*64];

  const int bm = blockIdx.x >> 5;
  const int bn = blockIdx.x & 31;
  const int tid = threadIdx.x;
  const int wv = tid >> 6, l = tid & 63;
  const int wm = wv >> 1, wn = wv & 1;
  const int c16 = l & 15, rq = l >> 4;

  const unsigned short* Ab = A  + (size_t)bm*128*1024;
  const unsigned short* Bb = Bw + (size_t)bn*128*1024;

  f32x4 acc[4][4];
#pragma unroll
  for (int i=0;i<4;++i)
#pragma unroll
    for (int j=0;j<4;++j) acc[i][j] = (f32x4){0.f,0.f,0.f,0.f};

  auto stage = [&](int buf, int kt){
    const int k0 = kt*64;
    const int rsub = wv*8 + (l>>3);
    const int col  = (l&7)*8;
#pragma unroll
    for (int is=0; is<4; ++is){
      const int row = is*32 + rsub;
      gload_lds16(Ab + (size_t)row*1024 + k0 + col, &Al[buf][row*64 + col]);
      gload_lds16(Bb + (size_t)row*1024 + k0 + col, &Bl[buf][row*64 + col]);
    }
  };

  stage(0, 0);
  asm volatile("s_waitcnt vmcnt(0)" ::: "memory");
  __syncthreads();

  for (int kt = 0; kt < 16; ++kt){
    const int cur = kt & 1;
    if (kt < 15) stage(cur^1, kt+1);
#pragma unroll
    for (int ks=0; ks<2; ++ks){
      s16x8 afr[4], bfr[4];
#pragma unroll
      for (int mi=0;mi<4;++mi)
        afr[mi] = *(const s16x8*)&Al[cur][(wm*64 + mi*16 + c16)*64 + ks*32 + rq*8];
#pragma unroll
      for (int ni=0;ni<4;++ni)
        bfr[ni] = *(const s16x8*)&Bl[cur][(wn*64 + ni*16 + c16)*64 + ks*32 + rq*8];
#pragma unroll
      for (int mi=0;mi<4;++mi)
#pragma unroll
        for (int ni=0;ni<4;++ni)
          acc[mi][ni] = MFMA_BF16(afr[mi], bfr[ni], acc[mi][ni]);
    }
    asm volatile("s_waitcnt vmcnt(0)" ::: "memory");
    __syncthreads();
  }

  const int crow0 = bm*128 + wm*64;
  const int ccol0 = bn*128 + wn*64;
#pragma unroll
  for (int ni=0;ni<4;++ni){
    const int col = ccol0 + ni*16 + c16;
    const float bsum = bih[col] + bhh[col];
#pragma unroll
    for (int mi=0;mi<4;++mi){
      const int row = crow0 + mi*16 + rq*4;
#pragma unroll
      for (int r=0;r<4;++r)
        C[(size_t)(row+r)*GDIM + col] = acc[mi][ni][r] + bsum;
    }
  }
}

// ---------------- persistent recurrence: R8 poll + R10 body (both HW-proven) ---
// 256 blocks x 512 threads = 4 batch-groups (bq: 16 rows) x 64 hidden-groups
// (hg: 16 cols -> 64 gate rows). Wave wv owns K-eighth [128wv,128wv+128) and
// loads its h fragments straight from LLC into registers (no LDS h-stage).
// Sync: monotone per-producer flags at LLC (sc0 sc1 -- the only verified
// cross-block path; R12's L2-scope attempt failed on HW). Wave 0 polls all 64
// domain flags (1 per lane, R8-proven fastest), barrier B0 releases the block.
// 3 barriers/step: B0 (h^t ready), B2 (dbuf partials), B3 (hsh).
// 2-slot ring safety: flag(t+1) follows B2(t)/B0(t) which joins all waves
// after wave 0 observed all 64 same-bq producers >= t.
__global__ __launch_bounds__(512,1) void lstm_rec(
    const unsigned short* __restrict__ whhb,   // bf16 [4096][1024]
    const float* __restrict__ xproj,           // fp32 [nsteps*64][4096]
    unsigned short* __restrict__ hring,        // bf16 [2][64*1024] (linear)
    float* __restrict__ cstate,                // fp32 [64*1024]
    float* __restrict__ outp,                  // fp32 d_out base
    unsigned int* __restrict__ bar,            // [256] flags, stride 32 uints
    int t0, int nsteps)
{
  const int tid = threadIdx.x;
  const int wv = tid >> 6, l = tid & 63;
  const int c16 = l & 15, rq = l >> 4;
  const int bq = blockIdx.x >> 6;             // batch group 0..3 (16 rows)
  const int hg = blockIdx.x & 63;             // hidden group 0..63 (16 cols)
  const int hc0 = hg * 16;
  const int b0  = bq * 16;
  const int em = tid >> 4, ec = tid & 15;     // epilogue (batch,col), tid<256

  __shared__ float part[2*8*16*68];                     // 69.6 KB dbuf partials
  __shared__ __align__(16) unsigned short hsh[256];     // 512 B h bf16 staging

  // ---- W_hh slice -> registers: gate-row local n = nt*16 + c16 (0..63),
  //      whh row = (n&3)*HID + hc0 + (n>>2); k = wv*128 + ks*32 + rq*8
  s16x8 breg[4][4];
#pragma unroll
  for (int nt = 0; nt < 4; ++nt){
    const int n = nt*16 + c16;
    const size_t grow = (size_t)(n & 3)*HID + hc0 + (n >> 2);
#pragma unroll
    for (int ks = 0; ks < 4; ++ks)
      breg[nt][ks] = *(const s16x8*)(whhb + grow*HID + wv*128 + ks*32 + rq*8);
  }

  float creg = 0.f, xp[4] = {0.f,0.f,0.f,0.f};
  if (tid < 256){
    creg = cstate[(size_t)(b0+em)*HID + hc0 + ec];
#pragma unroll
    for (int g = 0; g < 4; ++g)
      xp[g] = xproj[(size_t)(b0+em)*GDIM + g*HID + hc0 + ec];
  }

  // wave-0 poll target: lane l -> domain flag (bq, hg'=l)
  const unsigned int* myflag = bar + ((bq*64 + l) << 5);

  for (int t = t0; t < t0 + nsteps; ++t){
    // ---- wave 0: poll all 64 domain flags (1 per lane), divergent spin
    if (wv == 0){
      unsigned fv; int spins = 0;
      const unsigned ut = (unsigned)t;
      do {
        asm volatile("global_load_dword %0, %1, off sc0 sc1\n\ts_waitcnt vmcnt(0)"
                     : "=v"(fv) : "v"(myflag) : "memory");
        if (fv >= ut) break;
        if (++spins > 4) __builtin_amdgcn_s_sleep(1);
      } while (spins < (1 << 17));
    }
    __syncthreads();                                   // B0: h^t ready

    // ---- direct LLC -> register h fragments (this wave's k-eighth)
    const unsigned short* hb = hring + (size_t)(t & 1)*65536
                             + (size_t)(b0 + c16)*HID + wv*128 + rq*8;
    u32x4 af[4];
#define AL(K) asm volatile("global_load_dwordx4 %0, %1, off offset:%c2 sc0 sc1" \
                           : "=v"(af[K]) : "v"(hb), "i"((K)*64))
    AL(0); AL(1); AL(2); AL(3);
#undef AL
    asm volatile("s_waitcnt vmcnt(0)" ::: "memory");
    __builtin_amdgcn_sched_barrier(0);

    f32x4 acc[4];
#pragma unroll
    for (int nt = 0; nt < 4; ++nt) acc[nt] = (f32x4){0.f,0.f,0.f,0.f};
#pragma unroll
    for (int ks = 0; ks < 4; ++ks){
      const s16x8 a = __builtin_bit_cast(s16x8, af[ks]);
#pragma unroll
      for (int nt = 0; nt < 4; ++nt)
        acc[nt] = MFMA_BF16(a, breg[nt][ks], acc[nt]);
    }

    // ---- partials -> LDS (double-buffered): [buf][wv][m][n pad68]
    const int pbuf = t & 1;
    {
      float* pb = &part[(size_t)(pbuf*8 + wv)*16*68];
#pragma unroll
      for (int nt = 0; nt < 4; ++nt)
#pragma unroll
        for (int r = 0; r < 4; ++r)
          pb[(rq*4 + r)*68 + nt*16 + c16] = acc[nt][r];
    }
    __syncthreads();                                   // B2: partials ready

    // ---- epilogue (256 threads): vector-reduce 8 k-partials, activations
    float hval = 0.f;
    if (tid < 256){
      f32x4 vv = (f32x4){xp[0], xp[1], xp[2], xp[3]};
#pragma unroll
      for (int k8 = 0; k8 < 8; ++k8)
        vv += *(const f32x4*)&part[((size_t)(pbuf*8 + k8)*16 + em)*68 + ec*4];
      const float ig = 1.f/(1.f + __expf(-vv[0]));
      const float fg = 1.f/(1.f + __expf(-vv[1]));
      const float gg = tanhf(vv[2]);
      const float og = 1.f/(1.f + __expf(-vv[3]));
      creg = fg*creg + ig*gg;
      hval = og * tanhf(creg);
      hsh[em*16 + ec] = f2bf(hval);
    }
    __syncthreads();                                   // B3: hsh ready

    // ---- wave 0 lanes 0-31: store 32 x 16B h chunks -> drain -> flag
    if (tid < 32){
      const int row = l >> 1, ch = l & 1;
      const unsigned short* hp = hring + (size_t)((t+1) & 1)*65536
                               + (size_t)(b0 + row)*HID + hc0 + ch*8;
      u32x4 hv = *(const u32x4*)&hsh[row*16 + ch*8];
      asm volatile("global_store_dwordx4 %0, %1, off sc0 sc1"
                   :: "v"(hp), "v"(hv) : "memory");
      asm volatile("s_waitcnt vmcnt(0)" ::: "memory");
      if (tid == 0){
        unsigned int* fp = bar + ((unsigned)blockIdx.x << 5);
        unsigned int fv = (unsigned int)(t + 1);
        asm volatile("global_store_dword %0, %1, off sc0 sc1"
                     :: "v"(fp), "v"(fv) : "memory");
      }
    }

    // ---- off critical path: outputs, final state, xproj prefetch
    if (tid < 256){
      const size_t oidx = (size_t)(b0+em)*HID + hc0 + ec;
      outp[(size_t)t*65536 + oidx] = hval;
      if (t == SEQ-1){
        outp[(size_t)SEQ*65536 + oidx]         = hval;   // h_last
        outp[(size_t)SEQ*65536 + 65536 + oidx] = creg;   // c_last
      }
      if (t+1 < t0 + nsteps){
        const size_t xrow = (size_t)(t+1 - t0)*NBATCH + (b0+em);
#pragma unroll
        for (int g = 0; g < 4; ++g)
          xp[g] = xproj[xrow*GDIM + g*HID + hc0 + ec];
      }
    }
  }

  if (tid < 256)
    cstate[(size_t)(b0+em)*HID + hc0 + ec] = creg;
}

// ---------------------------------------------------------------------------
extern "C" void kernel_launch(void* const* d_in, const int* in_sizes, int n_in,
                              void* d_out, int out_size, void* d_ws, size_t ws_size,
                              hipStream_t stream)
{
  const float* inp = (const float*)d_in[0];
  const float* wih = (const float*)d_in[1];
  const float* whh = (const float*)d_in[2];
  const float* bih = (const float*)d_in[3];
  const float* bhh = (const float*)d_in[4];
  const float* h0  = (const float*)d_in[5];
  const float* c0  = (const float*)d_in[6];
  float* outp = (float*)d_out;

  auto alignup = [](size_t x){ return (x + 255) & ~(size_t)255; };
  auto need = [&](size_t ch)->size_t{
    size_t s = 0;
    s += alignup(ch*64*4096*4);          // xproj chunk
    s += alignup(ch*64*1024*2);          // in_bf16 chunk
    s += alignup((size_t)4096*1024*2);   // wih_bf16
    s += alignup((size_t)4096*1024*2);   // whh_bf16
    s += alignup((size_t)2*64*1024*2);   // h ring (2 slots)
    s += alignup((size_t)64*1024*4);     // cstate
    s += alignup((size_t)256*32*4);      // flags
    return s;
  };
  int CH = 512;
  while (CH > 2 && need(CH) > ws_size) CH >>= 1;

  char* w = (char*)d_ws;
  float*          xproj  = (float*)w;          w += alignup((size_t)CH*64*4096*4);
  unsigned short* in_bf  = (unsigned short*)w; w += alignup((size_t)CH*64*1024*2);
  unsigned short* wih_bf = (unsigned short*)w; w += alignup((size_t)4096*1024*2);
  unsigned short* whh_bf = (unsigned short*)w; w += alignup((size_t)4096*1024*2);
  unsigned short* hring  = (unsigned short*)w; w += alignup((size_t)2*64*1024*2);
  float*          cst    = (float*)w;          w += alignup((size_t)64*1024*4);
  unsigned int*   bar    = (unsigned int*)w;

  hipMemsetAsync(bar, 0, 256*32*4, stream);

  cvt_bf16<<<4096, 256, 0, stream>>>(wih, wih_bf, 4096*1024/4);
  cvt_bf16<<<4096, 256, 0, stream>>>(whh, whh_bf, 4096*1024/4);
  init_state<<<256, 256, 0, stream>>>(h0, c0, hring, cst);

  const int nch = SEQ / CH;
  for (int ci = 0; ci < nch; ++ci){
    const int t0 = ci * CH;
    const int n4 = CH*64*1024/4;
    cvt_bf16<<<(n4+255)/256, 256, 0, stream>>>(inp + (size_t)t0*65536, in_bf, n4);
    gemm_xproj<<<dim3((CH*64/128)*32), 256, 0, stream>>>(in_bf, wih_bf, bih, bhh,
                                                         xproj, CH*64);
    lstm_rec<<<dim3(256), dim3(512), 0, stream>>>(whh_bf, xproj, hring, cst, outp,
                                                  bar, t0, CH);
  }
}

// Round 14
// 1976.895 us; speedup vs baseline: 1.1997x; 1.1997x over previous
//
#include <hip/hip_runtime.h>
#include <stdint.h>

#define SEQ    512
#define NBATCH 64
#define HID    1024
#define GDIM   4096

typedef __attribute__((ext_vector_type(4))) float          f32x4;
typedef __attribute__((ext_vector_type(8))) short          s16x8;
typedef __attribute__((ext_vector_type(4))) unsigned short u16x4;
typedef __attribute__((ext_vector_type(4))) unsigned int   u32x4;

#define MFMA_BF16(a,b,c) __builtin_amdgcn_mfma_f32_16x16x32_bf16((a),(b),(c),0,0,0)

__device__ __forceinline__ unsigned short f2bf(float f){
  union { float f; unsigned u; } v; v.f = f;
  unsigned r = v.u + 0x7fffu + ((v.u >> 16) & 1u);
  return (unsigned short)(r >> 16);
}

// ---------------- fp32 -> bf16 bulk convert (n4 = elements/4) ----------------
__global__ __launch_bounds__(256) void cvt_bf16(const float* __restrict__ s,
                                                unsigned short* __restrict__ d, int n4){
  int i = blockIdx.x*256 + threadIdx.x;
  if (i >= n4) return;
  f32x4 v = *(const f32x4*)(s + (size_t)i*4);
  u16x4 o;
  o[0]=f2bf(v[0]); o[1]=f2bf(v[1]); o[2]=f2bf(v[2]); o[3]=f2bf(v[3]);
  *(u16x4*)(d + (size_t)i*4) = o;
}

// ---------------- init: h0 -> hring slot 0 (bf16, linear), c0 -> cstate ----
__global__ __launch_bounds__(256) void init_state(const float* __restrict__ h0,
                                                  const float* __restrict__ c0,
                                                  unsigned short* __restrict__ hring,
                                                  float* __restrict__ cstate){
  int i = blockIdx.x*256 + threadIdx.x;   // 65536 total
  hring[i]  = f2bf(h0[i]);
  cstate[i] = c0[i];
}

// ---------------- persistent fused LSTM (champion R8 body + shadow x-GEMM) -----
// 256 blocks x 512 threads = 4 batch-groups (bq: 16 rows) x 64 hidden-groups
// (hg: 16 cols -> 64 gate rows). Champion structure (845us/chunk, HW-proven):
// wave-0 poll of 64 domain flags -> B0; 32KB h stage to LDS (swizzled) -> B1;
// MFMA (kq = wv>>1 K-quarter, rh = wv&1 row-half) -> partials -> B2; epilogue
// -> B3; h-slice store + drain + flag (now on WAVE 7 so poller wave 0 is free).
// NEW: x-projection partials for step t+1 computed POST-FLAG, in the window
// where the block waits for its 63 peers. Hazards are barrier-spanned:
// write(t, post-flag) < B2(t+1) < read(t+1, epilogue) < B3(t+2) < write(t+2).
// This deletes gemm_xproj + the fp32 xproj buffer + chunking entirely.
__global__ __launch_bounds__(512,1) void lstm_rec(
    const unsigned short* __restrict__ whhb,   // bf16 [4096][1024]
    const unsigned short* __restrict__ wihb,   // bf16 [4096][1024]
    const unsigned short* __restrict__ xbf,    // bf16 [512*64][1024]
    const float* __restrict__ bih, const float* __restrict__ bhh,
    unsigned short* __restrict__ hring,        // bf16 [2][64*1024] (linear)
    float* __restrict__ cstate,                // fp32 [64*1024]
    float* __restrict__ outp,                  // fp32 d_out base
    unsigned int* __restrict__ bar,            // [256] flags, stride 32 uints
    int t0, int nsteps)
{
  const int tid = threadIdx.x;
  const int wv = tid >> 6, l = tid & 63;
  const int kq = wv >> 1, rh = wv & 1;
  const int c16 = l & 15, rq = l >> 4;
  const int bq = blockIdx.x >> 6;             // batch group 0..3 (16 rows)
  const int hg = blockIdx.x & 63;             // hidden group 0..63 (16 cols)
  const int hc0 = hg * 16;
  const int b0  = bq * 16;
  const int eb = tid >> 4, ec = tid & 15;     // epilogue (batch,col), tid<256
  const int sb = tid >> 5, cl0 = tid & 31;    // staging (batch row, chunk base)

  __shared__ s16x8 hls[16*128];                         // 32 KB staged h
  __shared__ float part[8*16*36];                       // 18.4 KB h partials
  __shared__ float part_x[2*8*16*36];                   // 36.9 KB x partials dbuf
  __shared__ __align__(16) unsigned short hsh[16*16];   // 512 B h staging

  // ---- W_hh and W_ih slices -> registers: gate row n = rh*32 + nt*16 + c16,
  //      weight row = (n&3)*HID + hc0 + (n>>2); k = kq*256 + ks*32 + rq*8
  s16x8 breg[2][8], bihr[2][8];
#pragma unroll
  for (int nt = 0; nt < 2; ++nt)
#pragma unroll
    for (int ks = 0; ks < 8; ++ks){
      const int n = rh*32 + nt*16 + c16;
      const size_t off = ((size_t)(n & 3)*HID + hc0 + (n >> 2))*HID
                       + kq*256 + ks*32 + rq*8;
      breg[nt][ks] = *(const s16x8*)(whhb + off);
      bihr[nt][ks] = *(const s16x8*)(wihb + off);
    }

  float creg = 0.f, bsum[4] = {0.f,0.f,0.f,0.f};
  if (tid < 256){
    creg = cstate[(size_t)(b0+eb)*HID + hc0 + ec];
#pragma unroll
    for (int g = 0; g < 4; ++g){
      const size_t bi = (size_t)g*HID + hc0 + ec;
      bsum[g] = bih[bi] + bhh[bi];
    }
  }

  const unsigned int* myflag = bar + ((bq*64 + l) << 5);

  // ---- x-phase helper values (same wave geometry as h-MFMA)
  // A-rows = batch c16; k = kq*256 + ks*32 + rq*8; B = bihr[nt][ks]
  // prologue: x partials for step t0 -> part_x[t0&1]
  {
    const unsigned short* xb = xbf + ((size_t)t0*NBATCH + b0 + c16)*HID
                             + kq*256 + rq*8;
    s16x8 ax[8];
#pragma unroll
    for (int ks = 0; ks < 8; ++ks)
      ax[ks] = *(const s16x8*)(xb + ks*32);
    f32x4 ax0 = (f32x4){0.f,0.f,0.f,0.f};
    f32x4 ax1 = (f32x4){0.f,0.f,0.f,0.f};
#pragma unroll
    for (int ks = 0; ks < 8; ++ks){
      ax0 = MFMA_BF16(ax[ks], bihr[0][ks], ax0);
      ax1 = MFMA_BF16(ax[ks], bihr[1][ks], ax1);
    }
    float* px = &part_x[(size_t)((t0 & 1)*8 + wv)*576];
#pragma unroll
    for (int r = 0; r < 4; ++r){
      px[(rq*4+r)*36 +      c16] = ax0[r];
      px[(rq*4+r)*36 + 16 + c16] = ax1[r];
    }
  }

  for (int t = t0; t < t0 + nsteps; ++t){
    // ---- wave 0: poll 64 domain flags (1 per lane), divergent spin
    if (wv == 0){
      unsigned fv; int spins = 0;
      const unsigned ut = (unsigned)t;
      do {
        asm volatile("global_load_dword %0, %1, off sc0 sc1\n\ts_waitcnt vmcnt(0)"
                     : "=v"(fv) : "v"(myflag) : "memory");
        if (fv >= ut) break;
        if (++spins > 4) __builtin_amdgcn_s_sleep(1);
      } while (spins < (1 << 17));
    }
    __syncthreads();                                   // B0: h^t ready

    // ---- stage h: 4 x 16B per thread (LLC), swizzled LDS write
    {
      const unsigned short* gb = hring + (size_t)(t & 1)*65536
                               + (size_t)(b0 + sb)*HID;
      u32x4 tmp[4];
#pragma unroll
      for (int i = 0; i < 4; ++i){
        const unsigned short* p = gb + (cl0 + 32*i)*8;
        asm volatile("global_load_dwordx4 %0, %1, off sc0 sc1"
                     : "=v"(tmp[i]) : "v"(p));
      }
      asm volatile("s_waitcnt vmcnt(0)" ::: "memory");
      __builtin_amdgcn_sched_barrier(0);
#pragma unroll
      for (int i = 0; i < 4; ++i){
        const int cl = cl0 + 32*i;
        hls[sb*128 + ((cl & ~7) | ((cl & 7) ^ (sb & 7)))] =
            __builtin_bit_cast(s16x8, tmp[i]);
      }
    }
    __syncthreads();                                   // B1: hls ready

    // ---- MFMA: this wave covers (K quarter kq, row half rh), 16 batch rows
    f32x4 acc0 = (f32x4){0.f,0.f,0.f,0.f};
    f32x4 acc1 = (f32x4){0.f,0.f,0.f,0.f};
    {
      s16x8 af[8];
#pragma unroll
      for (int ks = 0; ks < 8; ++ks){
        const int c = kq*32 + ks*4 + rq;
        af[ks] = hls[c16*128 + ((c & ~7) | ((c & 7) ^ (c16 & 7)))];
      }
#pragma unroll
      for (int ks = 0; ks < 8; ++ks){
        acc0 = MFMA_BF16(af[ks], breg[0][ks], acc0);
        acc1 = MFMA_BF16(af[ks], breg[1][ks], acc1);
      }
    }
#pragma unroll
    for (int r = 0; r < 4; ++r){
      part[wv*576 + (rq*4+r)*36 +      c16] = acc0[r];
      part[wv*576 + (rq*4+r)*36 + 16 + c16] = acc1[r];
    }
    __syncthreads();                                   // B2: partials ready

    // ---- epilogue (256 threads): bias + 4 h-partials + 4 x-partials per gate
    float hval = 0.f;
    const int pxb = (t & 1)*8;
    if (tid < 256){
      float v[4];
#pragma unroll
      for (int g = 0; g < 4; ++g){
        const int row = ec*4 + g;
        const int pl = (row >> 5);
        const int nl = row & 31;
        v[g] = bsum[g]
             + part[(0*2 + pl)*576 + eb*36 + nl]
             + part[(1*2 + pl)*576 + eb*36 + nl]
             + part[(2*2 + pl)*576 + eb*36 + nl]
             + part[(3*2 + pl)*576 + eb*36 + nl]
             + part_x[(size_t)(pxb + 0*2 + pl)*576 + eb*36 + nl]
             + part_x[(size_t)(pxb + 1*2 + pl)*576 + eb*36 + nl]
             + part_x[(size_t)(pxb + 2*2 + pl)*576 + eb*36 + nl]
             + part_x[(size_t)(pxb + 3*2 + pl)*576 + eb*36 + nl];
      }
      const float ig = 1.f/(1.f + __expf(-v[0]));
      const float fg = 1.f/(1.f + __expf(-v[1]));
      const float gg = tanhf(v[2]);
      const float og = 1.f/(1.f + __expf(-v[3]));
      creg = fg*creg + ig*gg;
      hval = og * tanhf(creg);
      hsh[eb*16 + ec] = f2bf(hval);
    }
    __syncthreads();                                   // B3: hsh ready

    // ---- WAVE 7 lanes 0-31: h slice store -> drain -> flag (wave 0 stays free)
    if (tid >= 448 && tid < 480){
      const int i32 = tid - 448;
      const int row = i32 >> 1, half = i32 & 1;
      const unsigned short* hp = hring + (size_t)((t+1) & 1)*65536
                               + (size_t)(b0 + row)*HID + hc0 + half*8;
      u32x4 hv = *(const u32x4*)&hsh[row*16 + half*8];
      asm volatile("global_store_dwordx4 %0, %1, off sc0 sc1"
                   :: "v"(hp), "v"(hv) : "memory");
      asm volatile("s_waitcnt vmcnt(0)" ::: "memory");
      if (i32 == 0){
        unsigned int* fp = bar + ((bq*64 + hg) << 5);
        unsigned int fv = (unsigned int)(t + 1);
        asm volatile("global_store_dword %0, %1, off sc0 sc1"
                     :: "v"(fp), "v"(fv) : "memory");
      }
    }

    // ---- SHADOW WORK (post-flag, peers still finishing): x partials for t+1
    {
      const int tn = (t+1 < SEQ) ? (t+1) : (SEQ-1);
      const unsigned short* xb = xbf + ((size_t)tn*NBATCH + b0 + c16)*HID
                               + kq*256 + rq*8;
      s16x8 ax[8];
#pragma unroll
      for (int ks = 0; ks < 8; ++ks)
        ax[ks] = *(const s16x8*)(xb + ks*32);
      f32x4 ax0 = (f32x4){0.f,0.f,0.f,0.f};
      f32x4 ax1 = (f32x4){0.f,0.f,0.f,0.f};
#pragma unroll
      for (int ks = 0; ks < 8; ++ks){
        ax0 = MFMA_BF16(ax[ks], bihr[0][ks], ax0);
        ax1 = MFMA_BF16(ax[ks], bihr[1][ks], ax1);
      }
      float* px = &part_x[(size_t)(((t+1) & 1)*8 + wv)*576];
#pragma unroll
      for (int r = 0; r < 4; ++r){
        px[(rq*4+r)*36 +      c16] = ax0[r];
        px[(rq*4+r)*36 + 16 + c16] = ax1[r];
      }
    }

    // ---- off critical path: outputs, final state
    if (tid < 256){
      const size_t oidx = (size_t)(b0+eb)*HID + hc0 + ec;
      outp[(size_t)t*65536 + oidx] = hval;
      if (t == SEQ-1){
        outp[(size_t)SEQ*65536 + oidx]         = hval;   // h_last
        outp[(size_t)SEQ*65536 + 65536 + oidx] = creg;   // c_last
      }
    }
  }

  if (tid < 256)
    cstate[(size_t)(b0+eb)*HID + hc0 + ec] = creg;
}

// ---------------------------------------------------------------------------
extern "C" void kernel_launch(void* const* d_in, const int* in_sizes, int n_in,
                              void* d_out, int out_size, void* d_ws, size_t ws_size,
                              hipStream_t stream)
{
  const float* inp = (const float*)d_in[0];
  const float* wih = (const float*)d_in[1];
  const float* whh = (const float*)d_in[2];
  const float* bih = (const float*)d_in[3];
  const float* bhh = (const float*)d_in[4];
  const float* h0  = (const float*)d_in[5];
  const float* c0  = (const float*)d_in[6];
  float* outp = (float*)d_out;

  auto alignup = [](size_t x){ return (x + 255) & ~(size_t)255; };
  char* w = (char*)d_ws;
  unsigned short* in_bf  = (unsigned short*)w; w += alignup((size_t)SEQ*64*1024*2);
  unsigned short* wih_bf = (unsigned short*)w; w += alignup((size_t)4096*1024*2);
  unsigned short* whh_bf = (unsigned short*)w; w += alignup((size_t)4096*1024*2);
  unsigned short* hring  = (unsigned short*)w; w += alignup((size_t)2*64*1024*2);
  float*          cst    = (float*)w;          w += alignup((size_t)64*1024*4);
  unsigned int*   bar    = (unsigned int*)w;

  hipMemsetAsync(bar, 0, 256*32*4, stream);

  cvt_bf16<<<SEQ*64*1024/4/256, 256, 0, stream>>>(inp, in_bf, SEQ*64*1024/4);
  cvt_bf16<<<4096, 256, 0, stream>>>(wih, wih_bf, 4096*1024/4);
  cvt_bf16<<<4096, 256, 0, stream>>>(whh, whh_bf, 4096*1024/4);
  init_state<<<256, 256, 0, stream>>>(h0, c0, hring, cst);

  lstm_rec<<<dim3(256), dim3(512), 0, stream>>>(whh_bf, wih_bf, in_bf, bih, bhh,
                                                hring, cst, outp, bar, 0, SEQ);
}

// Round 15
// 1912.002 us; speedup vs baseline: 1.2404x; 1.0339x over previous
//
#include <hip/hip_runtime.h>
#include <stdint.h>

#define SEQ    512
#define NBATCH 64
#define HID    1024
#define GDIM   4096

typedef __attribute__((ext_vector_type(4))) float          f32x4;
typedef __attribute__((ext_vector_type(8))) short          s16x8;
typedef __attribute__((ext_vector_type(4))) unsigned short u16x4;
typedef __attribute__((ext_vector_type(4))) unsigned int   u32x4;

#define MFMA_BF16(a,b,c) __builtin_amdgcn_mfma_f32_16x16x32_bf16((a),(b),(c),0,0,0)

__device__ __forceinline__ unsigned short f2bf(float f){
  union { float f; unsigned u; } v; v.f = f;
  unsigned r = v.u + 0x7fffu + ((v.u >> 16) & 1u);
  return (unsigned short)(r >> 16);
}

// ---------------- fp32 -> bf16 bulk convert (n4 = elements/4) ----------------
__global__ __launch_bounds__(256) void cvt_bf16(const float* __restrict__ s,
                                                unsigned short* __restrict__ d, int n4){
  int i = blockIdx.x*256 + threadIdx.x;
  if (i >= n4) return;
  f32x4 v = *(const f32x4*)(s + (size_t)i*4);
  u16x4 o;
  o[0]=f2bf(v[0]); o[1]=f2bf(v[1]); o[2]=f2bf(v[2]); o[3]=f2bf(v[3]);
  *(u16x4*)(d + (size_t)i*4) = o;
}

// ---------------- init: h0 -> hring slot 0 (bf16, linear), c0 -> cstate ----
__global__ __launch_bounds__(256) void init_state(const float* __restrict__ h0,
                                                  const float* __restrict__ c0,
                                                  unsigned short* __restrict__ hring,
                                                  float* __restrict__ cstate){
  int i = blockIdx.x*256 + threadIdx.x;   // 65536 total
  hring[i]  = f2bf(h0[i]);
  cstate[i] = c0[i];
}

// ---------------- persistent fused LSTM (R14 champion + early-issued x loads) --
// 256 blocks x 512 threads = 4 batch-groups (bq: 16 rows) x 64 hidden-groups
// (hg: 16 cols -> 64 gate rows). Structure (R14, HW-proven 1977us total):
// wave-0 poll of 64 domain flags -> B0; 32KB h stage to LDS (swizzled) -> B1;
// h-MFMA (kq = wv>>1 K-quarter, rh = wv&1 row-half) -> partials -> B2;
// epilogue (bias + h-part + x-part) -> B3; WAVE 7 h-slice store/drain/flag;
// shadow x-MFMA for t+1 post-flag. NEW in R15: the shadow's x fragment loads
// are ISSUED during the staging phase (untracked inline-asm loads -- the
// compiler emits no vmcnt for them at intervening barriers), so their L2
// latency hides under MFMA+B2+epilogue+B3 (~1.5us) and the shadow phase
// reduces to vmcnt(0) (already satisfied) + 16 MFMA + LDS write.
// Hazards barrier-spanned as in R14 (proven).
__global__ __launch_bounds__(512,1) void lstm_rec(
    const unsigned short* __restrict__ whhb,   // bf16 [4096][1024]
    const unsigned short* __restrict__ wihb,   // bf16 [4096][1024]
    const unsigned short* __restrict__ xbf,    // bf16 [512*64][1024]
    const float* __restrict__ bih, const float* __restrict__ bhh,
    unsigned short* __restrict__ hring,        // bf16 [2][64*1024] (linear)
    float* __restrict__ cstate,                // fp32 [64*1024]
    float* __restrict__ outp,                  // fp32 d_out base
    unsigned int* __restrict__ bar,            // [256] flags, stride 32 uints
    int t0, int nsteps)
{
  const int tid = threadIdx.x;
  const int wv = tid >> 6, l = tid & 63;
  const int kq = wv >> 1, rh = wv & 1;
  const int c16 = l & 15, rq = l >> 4;
  const int bq = blockIdx.x >> 6;             // batch group 0..3 (16 rows)
  const int hg = blockIdx.x & 63;             // hidden group 0..63 (16 cols)
  const int hc0 = hg * 16;
  const int b0  = bq * 16;
  const int eb = tid >> 4, ec = tid & 15;     // epilogue (batch,col), tid<256
  const int sb = tid >> 5, cl0 = tid & 31;    // staging (batch row, chunk base)

  __shared__ s16x8 hls[16*128];                         // 32 KB staged h
  __shared__ float part[8*16*36];                       // 18.4 KB h partials
  __shared__ float part_x[2*8*16*36];                   // 36.9 KB x partials dbuf
  __shared__ __align__(16) unsigned short hsh[16*16];   // 512 B h staging

  // ---- W_hh and W_ih slices -> registers: gate row n = rh*32 + nt*16 + c16,
  //      weight row = (n&3)*HID + hc0 + (n>>2); k = kq*256 + ks*32 + rq*8
  s16x8 breg[2][8], bihr[2][8];
#pragma unroll
  for (int nt = 0; nt < 2; ++nt)
#pragma unroll
    for (int ks = 0; ks < 8; ++ks){
      const int n = rh*32 + nt*16 + c16;
      const size_t off = ((size_t)(n & 3)*HID + hc0 + (n >> 2))*HID
                       + kq*256 + ks*32 + rq*8;
      breg[nt][ks] = *(const s16x8*)(whhb + off);
      bihr[nt][ks] = *(const s16x8*)(wihb + off);
    }

  float creg = 0.f, bsum[4] = {0.f,0.f,0.f,0.f};
  if (tid < 256){
    creg = cstate[(size_t)(b0+eb)*HID + hc0 + ec];
#pragma unroll
    for (int g = 0; g < 4; ++g){
      const size_t bi = (size_t)g*HID + hc0 + ec;
      bsum[g] = bih[bi] + bhh[bi];
    }
  }

  const unsigned int* myflag = bar + ((bq*64 + l) << 5);

  // ---- prologue: x partials for step t0 -> part_x[t0&1]
  {
    const unsigned short* xb = xbf + ((size_t)t0*NBATCH + b0 + c16)*HID
                             + kq*256 + rq*8;
    s16x8 ax[8];
#pragma unroll
    for (int ks = 0; ks < 8; ++ks)
      ax[ks] = *(const s16x8*)(xb + ks*32);
    f32x4 ax0 = (f32x4){0.f,0.f,0.f,0.f};
    f32x4 ax1 = (f32x4){0.f,0.f,0.f,0.f};
#pragma unroll
    for (int ks = 0; ks < 8; ++ks){
      ax0 = MFMA_BF16(ax[ks], bihr[0][ks], ax0);
      ax1 = MFMA_BF16(ax[ks], bihr[1][ks], ax1);
    }
    float* px = &part_x[(size_t)((t0 & 1)*8 + wv)*576];
#pragma unroll
    for (int r = 0; r < 4; ++r){
      px[(rq*4+r)*36 +      c16] = ax0[r];
      px[(rq*4+r)*36 + 16 + c16] = ax1[r];
    }
  }

  for (int t = t0; t < t0 + nsteps; ++t){
    // ---- wave 0: poll 64 domain flags (1 per lane), divergent spin
    if (wv == 0){
      unsigned fv; int spins = 0;
      const unsigned ut = (unsigned)t;
      do {
        asm volatile("global_load_dword %0, %1, off sc0 sc1\n\ts_waitcnt vmcnt(0)"
                     : "=v"(fv) : "v"(myflag) : "memory");
        if (fv >= ut) break;
        if (++spins > 4) __builtin_amdgcn_s_sleep(1);
      } while (spins < (1 << 17));
    }
    __syncthreads();                                   // B0: h^t ready

    // ---- stage h: 4 x 16B per thread (LLC), swizzled LDS write
    {
      const unsigned short* gb = hring + (size_t)(t & 1)*65536
                               + (size_t)(b0 + sb)*HID;
      u32x4 tmp[4];
#pragma unroll
      for (int i = 0; i < 4; ++i){
        const unsigned short* p = gb + (cl0 + 32*i)*8;
        asm volatile("global_load_dwordx4 %0, %1, off sc0 sc1"
                     : "=v"(tmp[i]) : "v"(p));
      }
      asm volatile("s_waitcnt vmcnt(0)" ::: "memory");
      __builtin_amdgcn_sched_barrier(0);
#pragma unroll
      for (int i = 0; i < 4; ++i){
        const int cl = cl0 + 32*i;
        hls[sb*128 + ((cl & ~7) | ((cl & 7) ^ (sb & 7)))] =
            __builtin_bit_cast(s16x8, tmp[i]);
      }
    }

    // ---- EARLY ISSUE: x fragments for t+1 (untracked asm loads; consumed in
    //      the shadow phase ~1.5us later -- L2 latency fully hidden)
    u32x4 axp[8];
    {
      const int tn = (t+1 < SEQ) ? (t+1) : (SEQ-1);
      const unsigned short* xb = xbf + ((size_t)tn*NBATCH + b0 + c16)*HID
                               + kq*256 + rq*8;
#define XA(K) asm volatile("global_load_dwordx4 %0, %1, off offset:%c2" \
                           : "=v"(axp[K]) : "v"(xb), "i"((K)*64))
      XA(0); XA(1); XA(2); XA(3); XA(4); XA(5); XA(6); XA(7);
#undef XA
    }
    __syncthreads();                                   // B1: hls ready

    // ---- h-MFMA: this wave covers (K quarter kq, row half rh), 16 batch rows
    f32x4 acc0 = (f32x4){0.f,0.f,0.f,0.f};
    f32x4 acc1 = (f32x4){0.f,0.f,0.f,0.f};
    {
      s16x8 af[8];
#pragma unroll
      for (int ks = 0; ks < 8; ++ks){
        const int c = kq*32 + ks*4 + rq;
        af[ks] = hls[c16*128 + ((c & ~7) | ((c & 7) ^ (c16 & 7)))];
      }
#pragma unroll
      for (int ks = 0; ks < 8; ++ks){
        acc0 = MFMA_BF16(af[ks], breg[0][ks], acc0);
        acc1 = MFMA_BF16(af[ks], breg[1][ks], acc1);
      }
    }
#pragma unroll
    for (int r = 0; r < 4; ++r){
      part[wv*576 + (rq*4+r)*36 +      c16] = acc0[r];
      part[wv*576 + (rq*4+r)*36 + 16 + c16] = acc1[r];
    }
    __syncthreads();                                   // B2: partials ready

    // ---- epilogue (256 threads): bias + 4 h-partials + 4 x-partials per gate
    float hval = 0.f;
    const int pxb = (t & 1)*8;
    if (tid < 256){
      float v[4];
#pragma unroll
      for (int g = 0; g < 4; ++g){
        const int row = ec*4 + g;
        const int pl = (row >> 5);
        const int nl = row & 31;
        v[g] = bsum[g]
             + part[(0*2 + pl)*576 + eb*36 + nl]
             + part[(1*2 + pl)*576 + eb*36 + nl]
             + part[(2*2 + pl)*576 + eb*36 + nl]
             + part[(3*2 + pl)*576 + eb*36 + nl]
             + part_x[(size_t)(pxb + 0*2 + pl)*576 + eb*36 + nl]
             + part_x[(size_t)(pxb + 1*2 + pl)*576 + eb*36 + nl]
             + part_x[(size_t)(pxb + 2*2 + pl)*576 + eb*36 + nl]
             + part_x[(size_t)(pxb + 3*2 + pl)*576 + eb*36 + nl];
      }
      const float ig = 1.f/(1.f + __expf(-v[0]));
      const float fg = 1.f/(1.f + __expf(-v[1]));
      const float gg = tanhf(v[2]);
      const float og = 1.f/(1.f + __expf(-v[3]));
      creg = fg*creg + ig*gg;
      hval = og * tanhf(creg);
      hsh[eb*16 + ec] = f2bf(hval);
    }
    __syncthreads();                                   // B3: hsh ready

    // ---- WAVE 7 lanes 0-31: h slice store -> drain -> flag (wave 0 stays free)
    if (tid >= 448 && tid < 480){
      const int i32 = tid - 448;
      const int row = i32 >> 1, half = i32 & 1;
      const unsigned short* hp = hring + (size_t)((t+1) & 1)*65536
                               + (size_t)(b0 + row)*HID + hc0 + half*8;
      u32x4 hv = *(const u32x4*)&hsh[row*16 + half*8];
      asm volatile("global_store_dwordx4 %0, %1, off sc0 sc1"
                   :: "v"(hp), "v"(hv) : "memory");
      asm volatile("s_waitcnt vmcnt(0)" ::: "memory");
      if (i32 == 0){
        unsigned int* fp = bar + ((bq*64 + hg) << 5);
        unsigned int fv = (unsigned int)(t + 1);
        asm volatile("global_store_dword %0, %1, off sc0 sc1"
                     :: "v"(fp), "v"(fv) : "memory");
      }
    }

    // ---- SHADOW (post-flag): x partials for t+1; loads already in flight
    {
      asm volatile("s_waitcnt vmcnt(0)" ::: "memory");
      __builtin_amdgcn_sched_barrier(0);
      f32x4 ax0 = (f32x4){0.f,0.f,0.f,0.f};
      f32x4 ax1 = (f32x4){0.f,0.f,0.f,0.f};
#pragma unroll
      for (int ks = 0; ks < 8; ++ks){
        const s16x8 a = __builtin_bit_cast(s16x8, axp[ks]);
        ax0 = MFMA_BF16(a, bihr[0][ks], ax0);
        ax1 = MFMA_BF16(a, bihr[1][ks], ax1);
      }
      float* px = &part_x[(size_t)(((t+1) & 1)*8 + wv)*576];
#pragma unroll
      for (int r = 0; r < 4; ++r){
        px[(rq*4+r)*36 +      c16] = ax0[r];
        px[(rq*4+r)*36 + 16 + c16] = ax1[r];
      }
    }

    // ---- off critical path: outputs, final state
    if (tid < 256){
      const size_t oidx = (size_t)(b0+eb)*HID + hc0 + ec;
      outp[(size_t)t*65536 + oidx] = hval;
      if (t == SEQ-1){
        outp[(size_t)SEQ*65536 + oidx]         = hval;   // h_last
        outp[(size_t)SEQ*65536 + 65536 + oidx] = creg;   // c_last
      }
    }
  }

  if (tid < 256)
    cstate[(size_t)(b0+eb)*HID + hc0 + ec] = creg;
}

// ---------------------------------------------------------------------------
extern "C" void kernel_launch(void* const* d_in, const int* in_sizes, int n_in,
                              void* d_out, int out_size, void* d_ws, size_t ws_size,
                              hipStream_t stream)
{
  const float* inp = (const float*)d_in[0];
  const float* wih = (const float*)d_in[1];
  const float* whh = (const float*)d_in[2];
  const float* bih = (const float*)d_in[3];
  const float* bhh = (const float*)d_in[4];
  const float* h0  = (const float*)d_in[5];
  const float* c0  = (const float*)d_in[6];
  float* outp = (float*)d_out;

  auto alignup = [](size_t x){ return (x + 255) & ~(size_t)255; };
  char* w = (char*)d_ws;
  unsigned short* in_bf  = (unsigned short*)w; w += alignup((size_t)SEQ*64*1024*2);
  unsigned short* wih_bf = (unsigned short*)w; w += alignup((size_t)4096*1024*2);
  unsigned short* whh_bf = (unsigned short*)w; w += alignup((size_t)4096*1024*2);
  unsigned short* hring  = (unsigned short*)w; w += alignup((size_t)2*64*1024*2);
  float*          cst    = (float*)w;          w += alignup((size_t)64*1024*4);
  unsigned int*   bar    = (unsigned int*)w;

  hipMemsetAsync(bar, 0, 256*32*4, stream);

  cvt_bf16<<<SEQ*64*1024/4/256, 256, 0, stream>>>(inp, in_bf, SEQ*64*1024/4);
  cvt_bf16<<<4096, 256, 0, stream>>>(wih, wih_bf, 4096*1024/4);
  cvt_bf16<<<4096, 256, 0, stream>>>(whh, whh_bf, 4096*1024/4);
  init_state<<<256, 256, 0, stream>>>(h0, c0, hring, cst);

  lstm_rec<<<dim3(256), dim3(512), 0, stream>>>(whh_bf, wih_bf, in_bf, bih, bhh,
                                                hring, cst, outp, bar, 0, SEQ);
}